// Round 1
// baseline (76.142 us; speedup 1.0000x reference)
//
#include <hip/hip_runtime.h>
#include <hip/hip_bf16.h>

#define NN 3072
#define RR 8

__global__ __launch_bounds__(256) void frd_kernel(
    const float* __restrict__ z,       // [N, R]
    const int*   __restrict__ seg,     // [N, N]
    const int*   __restrict__ cls,     // [N]
    const int*   __restrict__ batch,   // [N]
    float*       __restrict__ out)     // [N, N, R]
{
    const long long tid = (long long)blockIdx.x * blockDim.x + threadIdx.x;
    const long long total = (long long)NN * NN;
    if (tid >= total) return;

    const int i = (int)(tid / NN);
    const int j = (int)(tid - (long long)i * NN);

    // seg = seg_matrix + eye; seg_mask = (seg == 0). seg_matrix in {0,1},
    // so diag (value+1) is never 0 -> equivalent to (seg==0 && i!=j).
    const int s = seg[tid];

    // node_mask: label not in {24,25,26}; labels in [0,27) -> label < 24.
    const int ci = cls[i];          // wave-uniform (64 | NN)
    const int cj = cls[j];          // coalesced
    const int bi = batch[i];        // wave-uniform
    const int bj = batch[j];        // coalesced

    const bool pm = (s == 0) & (i != j) & (ci < 24) & (cj < 24) & (bi == bj);

    float4 lo, hi;
    if (pm) {
        const float4* zi = (const float4*)(z + (long long)i * RR);
        const float4* zj = (const float4*)(z + (long long)j * RR);
        const float4 a0 = zi[0], a1 = zi[1];
        const float4 b0 = zj[0], b1 = zj[1];
        lo = make_float4(a0.x * b0.x, a0.y * b0.y, a0.z * b0.z, a0.w * b0.w);
        hi = make_float4(a1.x * b1.x, a1.y * b1.y, a1.z * b1.z, a1.w * b1.w);
    } else {
        lo = make_float4(1.0f, 0.0f, 0.0f, 0.0f);
        hi = make_float4(0.0f, 0.0f, 0.0f, 0.0f);
    }

    float4* o = (float4*)(out + tid * RR);
    o[0] = lo;
    o[1] = hi;
}

extern "C" void kernel_launch(void* const* d_in, const int* in_sizes, int n_in,
                              void* d_out, int out_size, void* d_ws, size_t ws_size,
                              hipStream_t stream) {
    const float* z     = (const float*)d_in[0];
    const int*   seg   = (const int*)d_in[1];
    const int*   cls   = (const int*)d_in[2];
    const int*   batch = (const int*)d_in[3];
    float* out = (float*)d_out;

    const long long total = (long long)NN * NN;   // one thread per (i,j)
    const int block = 256;
    const int grid = (int)((total + block - 1) / block);
    frd_kernel<<<grid, block, 0, stream>>>(z, seg, cls, batch, out);
}